// Round 5
// baseline (4266.067 us; speedup 1.0000x reference)
//
#include <hip/hip_runtime.h>
#include <hip/hip_bf16.h>

// VanillaRNN: B=512, S=256, V=128, E=128, H=512  (float32 in/out)
// 256 persistent blocks, dynamically grouped by XCD (HW_REG_XCC_ID):
//   each XCD: 2 batch-groups (32 rows) x {8 stage0 blocks, 8 stage1 blocks} (64-col slices).
// Weights f16 transposed, held in REGISTERS (amdgpu_waves_per_eu(2) -> 256-VGPR budget,
// asm keep-alive pins). h0/h1 f16, 4-deep, exchanged through XCD-shared L2 with
// relaxed-atomic flags (no fences; L1 write-through, __syncthreads drains vmcnt,
// readers use sc0 atomic loads). Projection runs in stage0 blocks, 4 steps behind.

#define Bb 512
#define Ss 256
#define Vv 128
#define Ee 128
#define Hh 512

typedef _Float16 f16;
typedef __attribute__((ext_vector_type(8))) _Float16 f16x8;
typedef __attribute__((ext_vector_type(4))) float f32x4;

// ws layout
#define OFF_H0   0u            // [4][512][512] f16 = 2,097,152
#define OFF_H1   2097152u      // [4][512][512] f16 = 2,097,152
#define OFF_W0T  4194304u      // [512][640]  f16 (W0T[c][k], k<128:Wih0, else Whh0)
#define OFF_W1T  4849664u      // [512][1024] f16 (W1T[c][k], k<512:Wih1, else Whh1)
#define OFF_WOT  5898240u      // [128][512]  f16 (WoutT[v][k])
#define OFF_EMB  6029312u      // [128][128]  f16
#define OFF_FLAG 6062080u      // [16 groups][16] int
#define OFF_CTR  6063104u      // [16] int per-XCD slot counters
#define WS_TOTAL 6063168u

__device__ __forceinline__ f16x8 ld8(const f16* p) {
    return *reinterpret_cast<const f16x8*>(p);
}
// L2-coherent fragment load (bypasses L1 via agent-scope relaxed atomic 8B loads)
__device__ __forceinline__ f16x8 ld8_l2(const f16* p) {
    union { f16x8 v; unsigned long long q[2]; } u;
    const unsigned long long* qp = (const unsigned long long*)p;
    u.q[0] = __hip_atomic_load(qp + 0, __ATOMIC_RELAXED, __HIP_MEMORY_SCOPE_AGENT);
    u.q[1] = __hip_atomic_load(qp + 1, __ATOMIC_RELAXED, __HIP_MEMORY_SCOPE_AGENT);
    return u.v;
}
#define MFMA16(a, b, c) __builtin_amdgcn_mfma_f32_16x16x32_f16((a), (b), (c), 0, 0, 0)

__global__ void prep_kernel(const float* __restrict__ Wih0, const float* __restrict__ Whh0,
                            const float* __restrict__ Wih1, const float* __restrict__ Whh1,
                            const float* __restrict__ Wout, const float* __restrict__ emb,
                            char* __restrict__ ws)
{
    f16* w0t = (f16*)(ws + OFF_W0T);
    f16* w1t = (f16*)(ws + OFF_W1T);
    f16* wot = (f16*)(ws + OFF_WOT);
    f16* e16 = (f16*)(ws + OFF_EMB);
    const int N0 = 512 * 640, N1 = 512 * 1024, N2 = 128 * 512, NE = 128 * 128;
    int i = blockIdx.x * blockDim.x + threadIdx.x;
    if (i < N0) {
        int c = i / 640, k = i - c * 640;
        w0t[i] = (f16)((k < 128) ? Wih0[k * 512 + c] : Whh0[(k - 128) * 512 + c]);
    } else if (i < N0 + N1) {
        int j = i - N0;
        int c = j >> 10, k = j & 1023;
        w1t[j] = (f16)((k < 512) ? Wih1[k * 512 + c] : Whh1[(k - 512) * 512 + c]);
    } else if (i < N0 + N1 + N2) {
        int j = i - (N0 + N1);
        int v = j >> 9, k = j & 511;
        wot[j] = (f16)(Wout[k * 128 + v]);
    } else if (i < N0 + N1 + N2 + NE) {
        int j = i - (N0 + N1 + N2);
        e16[j] = (f16)(emb[j]);
    }
}

__global__ __launch_bounds__(512)
__attribute__((amdgpu_waves_per_eu(2)))          // allocator budget: 256 VGPR/wave (2 waves/SIMD)
void rnn_kernel(
    const int* __restrict__ x,
    const float* __restrict__ bih0, const float* __restrict__ bhh0,
    const float* __restrict__ bih1, const float* __restrict__ bhh1,
    const float* __restrict__ bout, float* __restrict__ out,
    f16* __restrict__ h0buf, f16* __restrict__ h1buf,
    const f16* __restrict__ w0t, const f16* __restrict__ w1t,
    const f16* __restrict__ wot, const f16* __restrict__ e16,
    int* __restrict__ flags, int* __restrict__ xcdctr)
{
    const int tid = threadIdx.x;

    // --- dynamic XCD-local group assignment (group's 16 blocks share one L2) ---
    __shared__ int sslot[2];
    if (tid == 0) {
        unsigned int xcc;
        asm volatile("s_getreg_b32 %0, hwreg(20, 0, 4)" : "=s"(xcc));   // HW_REG_XCC_ID
        int s = atomicAdd(&xcdctr[xcc & 15], 1);
        sslot[0] = (int)(xcc & 15);
        sslot[1] = s;
    }
    __syncthreads();
    const int xcd = sslot[0], slot = sslot[1];
    const int grp = xcd * 2 + (slot >> 4);   // batch group 0..15 (32 rows each)
    const int sub = slot & 15;
    const int stg = sub >> 3;                // 0 = layer0 (+projection), 1 = layer1
    const int jc  = sub & 7;                 // column slice 0..7 (64 cols)
    if (grp >= 16) return;
    const int row0 = grp * 32;
    const int col0 = jc * 64;

    int* gflags = flags + grp * 16;          // [0..7]=stage0, [8..15]=stage1

    __shared__ int tok[32];
    __shared__ float bs[64];

    const int lane = tid & 63;
    const int wv = tid >> 6;                 // wave 0..7
    const int mt = wv >> 2, nt = wv & 3;     // 2 M-tiles x 4 N-tiles
    const int ar = lane & 15;
    const int kg8 = (lane >> 4) << 3;
    const int arow = row0 + mt * 16 + ar;
    const int crow = row0 + mt * 16 + ((lane >> 4) << 2);
    const int ccol = col0 + nt * 16 + ar;

    if (tid < 64) {
        bs[tid] = (stg == 0) ? (bih0[col0 + tid] + bhh0[col0 + tid])
                             : (bih1[col0 + tid] + bhh1[col0 + tid]);
    }
    __syncthreads();
    const float cbias = bs[nt * 16 + ar];

    if (stg == 0) {
        // ---- layer 0: h0(t) = tanh([emb(x_t) | h0(t-1)] @ W0 + b0), plus projection of h1(t-4) ----
        f16x8 bfr[20];   // K=640, my 16-col slice, resident in registers
        {
            const f16* wp = w0t + ccol * 640 + kg8;
            #pragma unroll
            for (int kc = 0; kc < 20; ++kc) bfr[kc] = ld8(wp + kc * 32);
            #pragma unroll
            for (int kc = 0; kc < 20; ++kc) asm volatile("" : "+v"(bfr[kc]));
        }
        const int vcol = jc * 16 + ar;                 // logits column this block covers
        const float pbias = bout[vcol];
        const f16* pwb = wot + vcol * Hh + kg8;        // Wout B-frags: plain loads (L1-cached)
        const int prow_base = row0 + mt * 16;

        for (int t = 0; t < Ss; ++t) {
            if (tid >= 64 && tid < 96) tok[tid - 64] = x[(row0 + tid - 64) * Ss + t];
            if (tid < 16) {
                // lanes 0..7: stage0 flags >= t (h0(t-1) ready)
                // lanes 8..15: stage1 flags >= t-3 (anti-clobber h0(t-4); h1(t-4) ready for projection)
                const int tgt = (tid < 8) ? t : (t - 3);
                int it = 0;
                while (__hip_atomic_load(&gflags[tid], __ATOMIC_RELAXED, __HIP_MEMORY_SCOPE_AGENT) < tgt) {
                    if (++it > (1 << 18)) break;
                    __builtin_amdgcn_s_sleep(1);
                }
            }
            __syncthreads();
            // batched A loads, then MFMA with 4 parallel accumulators
            f16x8 ef[4];
            const f16* ea = e16 + tok[mt * 16 + ar] * Ee + kg8;
            #pragma unroll
            for (int kc = 0; kc < 4; ++kc) ef[kc] = ld8(ea + kc * 32);
            f16x8 hf[16];
            const f16* ha = h0buf + ((t + 3) & 3) * (Bb * Hh) + arow * Hh + kg8;
            #pragma unroll
            for (int kc = 0; kc < 16; ++kc) hf[kc] = ld8_l2(ha + kc * 32);
            f32x4 a0 = {0.f,0.f,0.f,0.f}, a1 = a0, a2 = a0, a3 = a0;
            a0 = MFMA16(ef[0], bfr[0], a0); a1 = MFMA16(ef[1], bfr[1], a1);
            a2 = MFMA16(ef[2], bfr[2], a2); a3 = MFMA16(ef[3], bfr[3], a3);
            #pragma unroll
            for (int kc = 0; kc < 16; kc += 4) {
                a0 = MFMA16(hf[kc + 0], bfr[4 + kc + 0], a0);
                a1 = MFMA16(hf[kc + 1], bfr[4 + kc + 1], a1);
                a2 = MFMA16(hf[kc + 2], bfr[4 + kc + 2], a2);
                a3 = MFMA16(hf[kc + 3], bfr[4 + kc + 3], a3);
            }
            f32x4 acc = (a0 + a1) + (a2 + a3);
            f16* ho = h0buf + (t & 3) * (Bb * Hh) + crow * Hh + ccol;
            #pragma unroll
            for (int i = 0; i < 4; ++i) ho[i * Hh] = (f16)(tanhf(acc[i] + cbias));
            // projection of h1(t-4) -> logits(t-4); rotates across wave pairs (wv&3 == t&3)
            if (t >= 4 && (wv & 3) == (t & 3)) {
                const int tp = t - 4;
                f16x8 pf[16];
                const f16* pa = h1buf + (tp & 3) * (Bb * Hh) + (prow_base + ar) * Hh + kg8;
                #pragma unroll
                for (int kc = 0; kc < 16; ++kc) pf[kc] = ld8_l2(pa + kc * 32);
                f32x4 p0 = {0.f,0.f,0.f,0.f}, p1 = p0, p2 = p0, p3 = p0;
                #pragma unroll
                for (int kc = 0; kc < 16; kc += 4) {
                    p0 = MFMA16(pf[kc + 0], ld8(pwb + (kc + 0) * 32), p0);
                    p1 = MFMA16(pf[kc + 1], ld8(pwb + (kc + 1) * 32), p1);
                    p2 = MFMA16(pf[kc + 2], ld8(pwb + (kc + 2) * 32), p2);
                    p3 = MFMA16(pf[kc + 3], ld8(pwb + (kc + 3) * 32), p3);
                }
                f32x4 pr = (p0 + p1) + (p2 + p3);
                float* op = out + (size_t)(prow_base + ((lane >> 4) << 2)) * (Ss * Vv) + tp * Vv + vcol;
                #pragma unroll
                for (int i = 0; i < 4; ++i) op[i * (Ss * Vv)] = pr[i] + pbias;
            }
            __syncthreads();   // drains vmcnt: h0 stores visible in L2 before flag
            if (tid == 0)
                __hip_atomic_store(&gflags[jc], t + 1, __ATOMIC_RELAXED, __HIP_MEMORY_SCOPE_AGENT);
        }
        // ---- tail: project h1(252..255); one step per wave (wv&3), both M-tiles (wv>>2) ----
        if (tid < 8) {
            int it = 0;
            while (__hip_atomic_load(&gflags[8 + tid], __ATOMIC_RELAXED, __HIP_MEMORY_SCOPE_AGENT) < Ss) {
                if (++it > (1 << 18)) break;
                __builtin_amdgcn_s_sleep(1);
            }
        }
        __syncthreads();
        {
            const int tp = 252 + (wv & 3);
            f16x8 pf[16];
            const f16* pa = h1buf + (tp & 3) * (Bb * Hh) + (prow_base + ar) * Hh + kg8;
            #pragma unroll
            for (int kc = 0; kc < 16; ++kc) pf[kc] = ld8_l2(pa + kc * 32);
            f32x4 p0 = {0.f,0.f,0.f,0.f}, p1 = p0, p2 = p0, p3 = p0;
            #pragma unroll
            for (int kc = 0; kc < 16; kc += 4) {
                p0 = MFMA16(pf[kc + 0], ld8(pwb + (kc + 0) * 32), p0);
                p1 = MFMA16(pf[kc + 1], ld8(pwb + (kc + 1) * 32), p1);
                p2 = MFMA16(pf[kc + 2], ld8(pwb + (kc + 2) * 32), p2);
                p3 = MFMA16(pf[kc + 3], ld8(pwb + (kc + 3) * 32), p3);
            }
            f32x4 pr = (p0 + p1) + (p2 + p3);
            float* op = out + (size_t)(prow_base + ((lane >> 4) << 2)) * (Ss * Vv) + tp * Vv + vcol;
            #pragma unroll
            for (int i = 0; i < 4; ++i) op[i * (Ss * Vv)] = pr[i] + pbias;
        }
    } else {
        // ---- layer 1: h1(t) = tanh([h0(t) | h1(t-1)] @ W1 + b1) ----
        f16x8 bfr[32];   // K=1024, my 16-col slice, resident in registers (128 VGPR)
        {
            const f16* wp = w1t + ccol * 1024 + kg8;
            #pragma unroll
            for (int kc = 0; kc < 32; ++kc) bfr[kc] = ld8(wp + kc * 32);
            #pragma unroll
            for (int kc = 0; kc < 32; ++kc) asm volatile("" : "+v"(bfr[kc]));
        }
        for (int t = 0; t < Ss; ++t) {
            if (tid < 16) {
                // lanes 0..7: stage0 flags >= t+1 (h0(t) ready, projection(t-4) done -> h1 slot t&3 free)
                // lanes 8..15: own stage1 flags >= t (h1(t-1) ready)
                const int tgt = (tid < 8) ? (t + 1) : t;
                int it = 0;
                while (__hip_atomic_load(&gflags[tid], __ATOMIC_RELAXED, __HIP_MEMORY_SCOPE_AGENT) < tgt) {
                    if (++it > (1 << 18)) break;
                    __builtin_amdgcn_s_sleep(1);
                }
            }
            __syncthreads();
            f32x4 a0 = {0.f,0.f,0.f,0.f}, a1 = a0, a2 = a0, a3 = a0;
            {
                f16x8 hf[16];
                const f16* h0a = h0buf + (t & 3) * (Bb * Hh) + arow * Hh + kg8;
                #pragma unroll
                for (int kc = 0; kc < 16; ++kc) hf[kc] = ld8_l2(h0a + kc * 32);
                #pragma unroll
                for (int kc = 0; kc < 16; kc += 4) {
                    a0 = MFMA16(hf[kc + 0], bfr[kc + 0], a0);
                    a1 = MFMA16(hf[kc + 1], bfr[kc + 1], a1);
                    a2 = MFMA16(hf[kc + 2], bfr[kc + 2], a2);
                    a3 = MFMA16(hf[kc + 3], bfr[kc + 3], a3);
                }
            }
            {
                f16x8 hf[16];
                const f16* h1a = h1buf + ((t + 3) & 3) * (Bb * Hh) + arow * Hh + kg8;
                #pragma unroll
                for (int kc = 0; kc < 16; ++kc) hf[kc] = ld8_l2(h1a + kc * 32);
                #pragma unroll
                for (int kc = 0; kc < 16; kc += 4) {
                    a0 = MFMA16(hf[kc + 0], bfr[16 + kc + 0], a0);
                    a1 = MFMA16(hf[kc + 1], bfr[16 + kc + 1], a1);
                    a2 = MFMA16(hf[kc + 2], bfr[16 + kc + 2], a2);
                    a3 = MFMA16(hf[kc + 3], bfr[16 + kc + 3], a3);
                }
            }
            f32x4 acc = (a0 + a1) + (a2 + a3);
            f16* ho = h1buf + (t & 3) * (Bb * Hh) + crow * Hh + ccol;
            #pragma unroll
            for (int i = 0; i < 4; ++i) ho[i * Hh] = (f16)(tanhf(acc[i] + cbias));
            __syncthreads();   // drains vmcnt: h1 stores visible in L2 before flag
            if (tid == 0)
                __hip_atomic_store(&gflags[8 + jc], t + 1, __ATOMIC_RELAXED, __HIP_MEMORY_SCOPE_AGENT);
        }
    }
}

extern "C" void kernel_launch(void* const* d_in, const int* in_sizes, int n_in,
                              void* d_out, int out_size, void* d_ws, size_t ws_size,
                              hipStream_t stream) {
    const int*   x    = (const int*)d_in[0];
    const float* emb  = (const float*)d_in[1];
    const float* Wih0 = (const float*)d_in[2];
    const float* bih0 = (const float*)d_in[3];
    const float* Whh0 = (const float*)d_in[4];
    const float* bhh0 = (const float*)d_in[5];
    const float* Wih1 = (const float*)d_in[6];
    const float* bih1 = (const float*)d_in[7];
    const float* Whh1 = (const float*)d_in[8];
    const float* bhh1 = (const float*)d_in[9];
    const float* Wout = (const float*)d_in[10];
    const float* bout = (const float*)d_in[11];
    float* out = (float*)d_out;
    char*  ws  = (char*)d_ws;

    // zero h buffers + flags + counters; weight regions overwritten by prep (stream-ordered)
    hipMemsetAsync(d_ws, 0, WS_TOTAL, stream);

    {
        const int total = 512 * 640 + 512 * 1024 + 128 * 512 + 128 * 128;
        prep_kernel<<<(total + 1023) / 1024, 1024, 0, stream>>>(Wih0, Whh0, Wih1, Whh1, Wout, emb, ws);
    }

    f16* h0buf = (f16*)(ws + OFF_H0);
    f16* h1buf = (f16*)(ws + OFF_H1);
    f16* w0t   = (f16*)(ws + OFF_W0T);
    f16* w1t   = (f16*)(ws + OFF_W1T);
    f16* wot   = (f16*)(ws + OFF_WOT);
    f16* e16   = (f16*)(ws + OFF_EMB);
    int* flags = (int*)(ws + OFF_FLAG);
    int* ctr   = (int*)(ws + OFF_CTR);

    void* args[] = { (void*)&x, (void*)&bih0, (void*)&bhh0, (void*)&bih1, (void*)&bhh1,
                     (void*)&bout, (void*)&out, (void*)&h0buf, (void*)&h1buf,
                     (void*)&w0t, (void*)&w1t, (void*)&wot, (void*)&e16,
                     (void*)&flags, (void*)&ctr };
    hipLaunchCooperativeKernel((void*)rnn_kernel, dim3(256), dim3(512), args, 0, stream);
}

// Round 6
// 2362.100 us; speedup vs baseline: 1.8060x; 1.8060x over previous
//
#include <hip/hip_runtime.h>
#include <hip/hip_bf16.h>

// VanillaRNN: B=512, S=256, V=128, E=128, H=512  (float32 in/out)
// 256 persistent blocks, dynamically grouped by XCD (HW_REG_XCC_ID):
//   each XCD: 2 batch-groups (32 rows) x {8 stage0 blocks, 8 stage1 blocks} (64-col slices).
// Weights f16 transposed, loaded once into register fragments. h0/h1 f16, 4-deep,
// exchanged through the XCD-shared L2 with PLAIN vector loads + one buffer_inv sc0
// (vL1 invalidate) per step; flags are relaxed agent atomics. L1 is write-through so
// producer stores are in L2 after the __syncthreads vmcnt drain.
// Projection runs in stage0 blocks, 4 steps behind, rotating wave pairs.

#define Bb 512
#define Ss 256
#define Vv 128
#define Ee 128
#define Hh 512

typedef _Float16 f16;
typedef __attribute__((ext_vector_type(8))) _Float16 f16x8;
typedef __attribute__((ext_vector_type(4))) float f32x4;

// ws layout
#define OFF_H0   0u            // [4][512][512] f16 = 2,097,152
#define OFF_H1   2097152u      // [4][512][512] f16 = 2,097,152
#define OFF_W0T  4194304u      // [512][640]  f16 (W0T[c][k], k<128:Wih0, else Whh0)
#define OFF_W1T  4849664u      // [512][1024] f16 (W1T[c][k], k<512:Wih1, else Whh1)
#define OFF_WOT  5898240u      // [128][512]  f16 (WoutT[v][k])
#define OFF_EMB  6029312u      // [128][128]  f16
#define OFF_FLAG 6062080u      // [16 groups][16] int
#define OFF_CTR  6063104u      // [16] int per-XCD slot counters
#define WS_TOTAL 6063168u

__device__ __forceinline__ f16x8 ld8(const f16* p) {
    return *reinterpret_cast<const f16x8*>(p);
}
// Invalidate this CU's vector L1 (write-through cache) so subsequent plain loads
// observe the XCD-shared L2, where same-XCD producers' stores already landed.
#define INV_L1() asm volatile("buffer_inv sc0" ::: "memory")
#define MFMA16(a, b, c) __builtin_amdgcn_mfma_f32_16x16x32_f16((a), (b), (c), 0, 0, 0)

__global__ void prep_kernel(const float* __restrict__ Wih0, const float* __restrict__ Whh0,
                            const float* __restrict__ Wih1, const float* __restrict__ Whh1,
                            const float* __restrict__ Wout, const float* __restrict__ emb,
                            char* __restrict__ ws)
{
    f16* w0t = (f16*)(ws + OFF_W0T);
    f16* w1t = (f16*)(ws + OFF_W1T);
    f16* wot = (f16*)(ws + OFF_WOT);
    f16* e16 = (f16*)(ws + OFF_EMB);
    const int N0 = 512 * 640, N1 = 512 * 1024, N2 = 128 * 512, NE = 128 * 128;
    int i = blockIdx.x * blockDim.x + threadIdx.x;
    if (i < N0) {
        int c = i / 640, k = i - c * 640;
        w0t[i] = (f16)((k < 128) ? Wih0[k * 512 + c] : Whh0[(k - 128) * 512 + c]);
    } else if (i < N0 + N1) {
        int j = i - N0;
        int c = j >> 10, k = j & 1023;
        w1t[j] = (f16)((k < 512) ? Wih1[k * 512 + c] : Whh1[(k - 512) * 512 + c]);
    } else if (i < N0 + N1 + N2) {
        int j = i - (N0 + N1);
        int v = j >> 9, k = j & 511;
        wot[j] = (f16)(Wout[k * 128 + v]);
    } else if (i < N0 + N1 + N2 + NE) {
        int j = i - (N0 + N1 + N2);
        e16[j] = (f16)(emb[j]);
    }
}

__global__ __launch_bounds__(512, 2)        // min 2 waves/EU -> 256-VGPR budget, 1 block/CU
void rnn_kernel(
    const int* __restrict__ x,
    const float* __restrict__ bih0, const float* __restrict__ bhh0,
    const float* __restrict__ bih1, const float* __restrict__ bhh1,
    const float* __restrict__ bout, float* __restrict__ out,
    f16* __restrict__ h0buf, f16* __restrict__ h1buf,
    const f16* __restrict__ w0t, const f16* __restrict__ w1t,
    const f16* __restrict__ wot, const f16* __restrict__ e16,
    int* __restrict__ flags, int* __restrict__ xcdctr)
{
    const int tid = threadIdx.x;

    // --- dynamic XCD-local group assignment (group's 16 blocks share one L2) ---
    __shared__ int sslot[2];
    if (tid == 0) {
        unsigned int xcc;
        asm volatile("s_getreg_b32 %0, hwreg(20, 0, 4)" : "=s"(xcc));   // HW_REG_XCC_ID
        int s = atomicAdd(&xcdctr[xcc & 15], 1);
        sslot[0] = (int)(xcc & 15);
        sslot[1] = s;
    }
    __syncthreads();
    const int xcd = sslot[0], slot = sslot[1];
    const int grp = xcd * 2 + (slot >> 4);   // batch group 0..15 (32 rows each)
    const int sub = slot & 15;
    const int stg = sub >> 3;                // 0 = layer0 (+projection), 1 = layer1
    const int jc  = sub & 7;                 // column slice 0..7 (64 cols)
    if (grp >= 16) return;
    const int row0 = grp * 32;
    const int col0 = jc * 64;

    int* gflags = flags + grp * 16;          // [0..7]=stage0, [8..15]=stage1

    __shared__ int tok[32];
    __shared__ float bs[64];

    const int lane = tid & 63;
    const int wv = tid >> 6;                 // wave 0..7
    const int mt = wv >> 2, nt = wv & 3;     // 2 M-tiles x 4 N-tiles
    const int ar = lane & 15;
    const int kg8 = (lane >> 4) << 3;
    const int arow = row0 + mt * 16 + ar;
    const int crow = row0 + mt * 16 + ((lane >> 4) << 2);
    const int ccol = col0 + nt * 16 + ar;

    if (tid < 64) {
        bs[tid] = (stg == 0) ? (bih0[col0 + tid] + bhh0[col0 + tid])
                             : (bih1[col0 + tid] + bhh1[col0 + tid]);
    }
    __syncthreads();
    const float cbias = bs[nt * 16 + ar];

    if (stg == 0) {
        // ---- layer 0: h0(t) = tanh([emb(x_t) | h0(t-1)] @ W0 + b0), plus projection of h1(t-4) ----
        f16x8 bfr[20];   // K=640, my 16-col slice
        {
            const f16* wp = w0t + ccol * 640 + kg8;
            #pragma unroll
            for (int kc = 0; kc < 20; ++kc) bfr[kc] = ld8(wp + kc * 32);
            #pragma unroll
            for (int kc = 0; kc < 20; ++kc) asm volatile("" : "+v"(bfr[kc]));
        }
        const int vcol = jc * 16 + ar;                 // logits column this block covers
        const float pbias = bout[vcol];
        const f16* pwb = wot + vcol * Hh + kg8;        // Wout B-frags (read-only)
        const int prow_base = row0 + mt * 16;

        for (int t = 0; t < Ss; ++t) {
            if (tid >= 64 && tid < 96) tok[tid - 64] = x[(row0 + tid - 64) * Ss + t];
            if (tid < 16) {
                // lanes 0..7: stage0 flags >= t (h0(t-1) ready)
                // lanes 8..15: stage1 flags >= t-3 (anti-clobber h0(t-4); h1(t-4) ready for projection)
                const int tgt = (tid < 8) ? t : (t - 3);
                int it = 0;
                while (__hip_atomic_load(&gflags[tid], __ATOMIC_RELAXED, __HIP_MEMORY_SCOPE_AGENT) < tgt) {
                    if (++it > (1 << 18)) break;
                    __builtin_amdgcn_s_sleep(1);
                }
            }
            __syncthreads();
            INV_L1();   // L1 may hold stale lines for these addrs (written 4 steps ago); L2 is fresh
            // batched A loads (plain, pipelined), then MFMA with 4 parallel accumulators
            f16x8 ef[4];
            const f16* ea = e16 + tok[mt * 16 + ar] * Ee + kg8;
            #pragma unroll
            for (int kc = 0; kc < 4; ++kc) ef[kc] = ld8(ea + kc * 32);
            f16x8 hf[16];
            const f16* ha = h0buf + ((t + 3) & 3) * (Bb * Hh) + arow * Hh + kg8;
            #pragma unroll
            for (int kc = 0; kc < 16; ++kc) hf[kc] = ld8(ha + kc * 32);
            f32x4 a0 = {0.f,0.f,0.f,0.f}, a1 = a0, a2 = a0, a3 = a0;
            a0 = MFMA16(ef[0], bfr[0], a0); a1 = MFMA16(ef[1], bfr[1], a1);
            a2 = MFMA16(ef[2], bfr[2], a2); a3 = MFMA16(ef[3], bfr[3], a3);
            #pragma unroll
            for (int kc = 0; kc < 16; kc += 4) {
                a0 = MFMA16(hf[kc + 0], bfr[4 + kc + 0], a0);
                a1 = MFMA16(hf[kc + 1], bfr[4 + kc + 1], a1);
                a2 = MFMA16(hf[kc + 2], bfr[4 + kc + 2], a2);
                a3 = MFMA16(hf[kc + 3], bfr[4 + kc + 3], a3);
            }
            f32x4 acc = (a0 + a1) + (a2 + a3);
            f16* ho = h0buf + (t & 3) * (Bb * Hh) + crow * Hh + ccol;
            #pragma unroll
            for (int i = 0; i < 4; ++i) ho[i * Hh] = (f16)(tanhf(acc[i] + cbias));
            // projection of h1(t-4) -> logits(t-4); rotates across wave pairs (wv&3 == t&3)
            if (t >= 4 && (wv & 3) == (t & 3)) {
                const int tp = t - 4;
                f16x8 pf[16];
                const f16* pa = h1buf + (tp & 3) * (Bb * Hh) + (prow_base + ar) * Hh + kg8;
                #pragma unroll
                for (int kc = 0; kc < 16; ++kc) pf[kc] = ld8(pa + kc * 32);
                f32x4 p0 = {0.f,0.f,0.f,0.f}, p1 = p0, p2 = p0, p3 = p0;
                #pragma unroll
                for (int kc = 0; kc < 16; kc += 4) {
                    p0 = MFMA16(pf[kc + 0], ld8(pwb + (kc + 0) * 32), p0);
                    p1 = MFMA16(pf[kc + 1], ld8(pwb + (kc + 1) * 32), p1);
                    p2 = MFMA16(pf[kc + 2], ld8(pwb + (kc + 2) * 32), p2);
                    p3 = MFMA16(pf[kc + 3], ld8(pwb + (kc + 3) * 32), p3);
                }
                f32x4 pr = (p0 + p1) + (p2 + p3);
                float* op = out + (size_t)(prow_base + ((lane >> 4) << 2)) * (Ss * Vv) + tp * Vv + vcol;
                #pragma unroll
                for (int i = 0; i < 4; ++i) op[i * (Ss * Vv)] = pr[i] + pbias;
            }
            __syncthreads();   // drains vmcnt: h0 stores (write-through L1) are in L2 before flag
            if (tid == 0)
                __hip_atomic_store(&gflags[jc], t + 1, __ATOMIC_RELAXED, __HIP_MEMORY_SCOPE_AGENT);
        }
        // ---- tail: project h1(252..255); one step per wave (wv&3), both M-tiles (wv>>2) ----
        if (tid < 8) {
            int it = 0;
            while (__hip_atomic_load(&gflags[8 + tid], __ATOMIC_RELAXED, __HIP_MEMORY_SCOPE_AGENT) < Ss) {
                if (++it > (1 << 18)) break;
                __builtin_amdgcn_s_sleep(1);
            }
        }
        __syncthreads();
        INV_L1();
        {
            const int tp = 252 + (wv & 3);
            f16x8 pf[16];
            const f16* pa = h1buf + (tp & 3) * (Bb * Hh) + (prow_base + ar) * Hh + kg8;
            #pragma unroll
            for (int kc = 0; kc < 16; ++kc) pf[kc] = ld8(pa + kc * 32);
            f32x4 p0 = {0.f,0.f,0.f,0.f}, p1 = p0, p2 = p0, p3 = p0;
            #pragma unroll
            for (int kc = 0; kc < 16; kc += 4) {
                p0 = MFMA16(pf[kc + 0], ld8(pwb + (kc + 0) * 32), p0);
                p1 = MFMA16(pf[kc + 1], ld8(pwb + (kc + 1) * 32), p1);
                p2 = MFMA16(pf[kc + 2], ld8(pwb + (kc + 2) * 32), p2);
                p3 = MFMA16(pf[kc + 3], ld8(pwb + (kc + 3) * 32), p3);
            }
            f32x4 pr = (p0 + p1) + (p2 + p3);
            float* op = out + (size_t)(prow_base + ((lane >> 4) << 2)) * (Ss * Vv) + tp * Vv + vcol;
            #pragma unroll
            for (int i = 0; i < 4; ++i) op[i * (Ss * Vv)] = pr[i] + pbias;
        }
    } else {
        // ---- layer 1: h1(t) = tanh([h0(t) | h1(t-1)] @ W1 + b1) ----
        f16x8 bfr[32];   // K=1024, my 16-col slice
        {
            const f16* wp = w1t + ccol * 1024 + kg8;
            #pragma unroll
            for (int kc = 0; kc < 32; ++kc) bfr[kc] = ld8(wp + kc * 32);
            #pragma unroll
            for (int kc = 0; kc < 32; ++kc) asm volatile("" : "+v"(bfr[kc]));
        }
        for (int t = 0; t < Ss; ++t) {
            if (tid < 16) {
                // lanes 0..7: stage0 flags >= t+1 (h0(t) ready, projection(t-4) done -> h1 slot t&3 free)
                // lanes 8..15: own stage1 flags >= t (h1(t-1) ready)
                const int tgt = (tid < 8) ? (t + 1) : t;
                int it = 0;
                while (__hip_atomic_load(&gflags[tid], __ATOMIC_RELAXED, __HIP_MEMORY_SCOPE_AGENT) < tgt) {
                    if (++it > (1 << 18)) break;
                    __builtin_amdgcn_s_sleep(1);
                }
            }
            __syncthreads();
            INV_L1();   // drop stale L1 lines; fresh h0(t)/h1(t-1) are in the shared XCD L2
            f32x4 a0 = {0.f,0.f,0.f,0.f}, a1 = a0, a2 = a0, a3 = a0;
            {
                f16x8 hf[16];
                const f16* h0a = h0buf + (t & 3) * (Bb * Hh) + arow * Hh + kg8;
                #pragma unroll
                for (int kc = 0; kc < 16; ++kc) hf[kc] = ld8(h0a + kc * 32);
                #pragma unroll
                for (int kc = 0; kc < 16; kc += 4) {
                    a0 = MFMA16(hf[kc + 0], bfr[kc + 0], a0);
                    a1 = MFMA16(hf[kc + 1], bfr[kc + 1], a1);
                    a2 = MFMA16(hf[kc + 2], bfr[kc + 2], a2);
                    a3 = MFMA16(hf[kc + 3], bfr[kc + 3], a3);
                }
            }
            {
                f16x8 hf[16];
                const f16* h1a = h1buf + ((t + 3) & 3) * (Bb * Hh) + arow * Hh + kg8;
                #pragma unroll
                for (int kc = 0; kc < 16; ++kc) hf[kc] = ld8(h1a + kc * 32);
                #pragma unroll
                for (int kc = 0; kc < 16; kc += 4) {
                    a0 = MFMA16(hf[kc + 0], bfr[16 + kc + 0], a0);
                    a1 = MFMA16(hf[kc + 1], bfr[16 + kc + 1], a1);
                    a2 = MFMA16(hf[kc + 2], bfr[16 + kc + 2], a2);
                    a3 = MFMA16(hf[kc + 3], bfr[16 + kc + 3], a3);
                }
            }
            f32x4 acc = (a0 + a1) + (a2 + a3);
            f16* ho = h1buf + (t & 3) * (Bb * Hh) + crow * Hh + ccol;
            #pragma unroll
            for (int i = 0; i < 4; ++i) ho[i * Hh] = (f16)(tanhf(acc[i] + cbias));
            __syncthreads();   // drains vmcnt: h1 stores in L2 before flag
            if (tid == 0)
                __hip_atomic_store(&gflags[8 + jc], t + 1, __ATOMIC_RELAXED, __HIP_MEMORY_SCOPE_AGENT);
        }
    }
}

extern "C" void kernel_launch(void* const* d_in, const int* in_sizes, int n_in,
                              void* d_out, int out_size, void* d_ws, size_t ws_size,
                              hipStream_t stream) {
    const int*   x    = (const int*)d_in[0];
    const float* emb  = (const float*)d_in[1];
    const float* Wih0 = (const float*)d_in[2];
    const float* bih0 = (const float*)d_in[3];
    const float* Whh0 = (const float*)d_in[4];
    const float* bhh0 = (const float*)d_in[5];
    const float* Wih1 = (const float*)d_in[6];
    const float* bih1 = (const float*)d_in[7];
    const float* Whh1 = (const float*)d_in[8];
    const float* bhh1 = (const float*)d_in[9];
    const float* Wout = (const float*)d_in[10];
    const float* bout = (const float*)d_in[11];
    float* out = (float*)d_out;
    char*  ws  = (char*)d_ws;

    // zero h buffers + flags + counters; weight regions overwritten by prep (stream-ordered)
    hipMemsetAsync(d_ws, 0, WS_TOTAL, stream);

    {
        const int total = 512 * 640 + 512 * 1024 + 128 * 512 + 128 * 128;
        prep_kernel<<<(total + 1023) / 1024, 1024, 0, stream>>>(Wih0, Whh0, Wih1, Whh1, Wout, emb, ws);
    }

    f16* h0buf = (f16*)(ws + OFF_H0);
    f16* h1buf = (f16*)(ws + OFF_H1);
    f16* w0t   = (f16*)(ws + OFF_W0T);
    f16* w1t   = (f16*)(ws + OFF_W1T);
    f16* wot   = (f16*)(ws + OFF_WOT);
    f16* e16   = (f16*)(ws + OFF_EMB);
    int* flags = (int*)(ws + OFF_FLAG);
    int* ctr   = (int*)(ws + OFF_CTR);

    void* args[] = { (void*)&x, (void*)&bih0, (void*)&bhh0, (void*)&bih1, (void*)&bhh1,
                     (void*)&bout, (void*)&out, (void*)&h0buf, (void*)&h1buf,
                     (void*)&w0t, (void*)&w1t, (void*)&wot, (void*)&e16,
                     (void*)&flags, (void*)&ctr };
    hipLaunchCooperativeKernel((void*)rnn_kernel, dim3(256), dim3(512), args, 0, stream);
}